// Round 1
// baseline (227.049 us; speedup 1.0000x reference)
//
#include <hip/hip_runtime.h>
#include <math.h>

// B=64, A=64, MULS=((64,0),(32,1),(16,2)) -> DIM_IN=240, NB=32, H=128, MOUT=112
#define H_ 128
#define NB_ 32

#define INV_STEP 3.1f
#define HALF_PI 1.57079632679489662f
#define INV_SQRT_NB 0.17677669529663689f
#define INV_SQRT_H 0.08838834764831845f
#define NORM0 0.125f
#define NORM1 0.10206207261596575f
#define NORM2 0.11180339887498948f
#define S3 1.7320508075688772f
#define S5 2.23606797749979f
#define S15 3.872983346207417f
#define LN2 0.6931471805599453f

typedef __attribute__((ext_vector_type(8))) _Float16 half8;
typedef __attribute__((ext_vector_type(4))) float f32x4;

__device__ __forceinline__ float ssp_f(float x) {
    float t = 5.0f * x;
    float s = fmaxf(t, 0.0f) + __logf(1.0f + __expf(-fabsf(t)));
    return (s - LN2) * 0.2f;
}
__device__ __forceinline__ float sp_f(float x) {
    float t = 5.0f * x;
    float s = fmaxf(t, 0.0f) + __logf(1.0f + __expf(-fabsf(t)));
    return s * 0.2f;
}

// ---------------------------------------------------------------------------
// w2half: W2 (fp32 row-major) -> fp16 MFMA-B-fragment order in ws.
// pos = ((kt*8+nt)*64 + lane)*8 + j ; k = kt*32+(lane>>4)*8+j ; n = nt*16+(lane&15)
// ---------------------------------------------------------------------------
__global__ void w2half(const float* __restrict__ W2, _Float16* __restrict__ w2f) {
    const int e0 = (blockIdx.x * 256 + threadIdx.x) * 4;
    #pragma unroll
    for (int t = 0; t < 4; ++t) {
        const int pos = e0 + t;
        const int j = pos & 7, lane = (pos >> 3) & 63, fn = pos >> 9;
        const int kt = fn >> 3, nt = fn & 7;
        const int k = kt * 32 + (lane >> 4) * 8 + j;
        const int n = nt * 16 + (lane & 15);
        w2f[pos] = (_Float16)W2[k * 128 + n];
    }
}

// ---------------------------------------------------------------------------
// pair4: one block per (z, 8-b-group); LDS trimmed to 40800 B (-> 40960
// rounded) so 4 blocks/CU fit (was 72 KB -> 2 blocks/CU, Occupancy 19%).
//   - H2 transpose: per-kt per-wave fp16 scratch [16 a][32+8 h2] (1.25 KB/wave)
//     instead of a 34 KB full-width fp32 buffer. fp16 store is rounding-
//     identical to the old store-fp32-then-convert path (values feed fp16
//     MFMA either way).
//   - sYw: single-p [4][16][8]; Y recomputed per-p in the epilogue (quad==0)
//     from ax/ay/az + sPosB; the same math was deleted from the prologue.
//   - sRep staging removed: V-compute reads rep rows from global (wave-
//     uniform addresses -> L1 broadcast; startup only).
// ---------------------------------------------------------------------------
__global__ __launch_bounds__(256, 4)
void pair4(const float* __restrict__ rep, const float* __restrict__ geom,
           const float* __restrict__ W1, const float* __restrict__ W3,
           const _Float16* __restrict__ w2f, float* __restrict__ partial) {
    const int bg = blockIdx.x;           // b in [8bg, 8bg+8)
    const int z  = blockIdx.y;
    const int tid = threadIdx.x;
    const int wv = tid >> 6, lane = tid & 63;
    const int m = lane & 15, quad = lane >> 4;

    __shared__ __align__(16) _Float16 sVf[16384];      // 32768 B  [b][kt][lane][j]
    __shared__ __align__(16) _Float16 sH2t[4][16][40]; // 5120 B   per-wave [a][h2local+pad]
    __shared__ float sYw[4][16][8];                    // 2048 B
    __shared__ float sPosA[192];                       // 768 B
    __shared__ float sPosB[24];                        // 96 B
    // total 40800 B -> 40960 rounded -> 4 blocks/CU exactly

    // ---- startup: stage geom ----
    if (tid < 192) sPosA[tid] = geom[z * 192 + tid];
    else if (tid < 216) sPosB[tid - 192] = geom[((size_t)z * 64 + bg * 8) * 3 + (tid - 192)];

    // ---- V compute: 1024 slots (b,h); emit fp16 B-frags (16 n's incl. zeros) ----
    // rep read straight from global: per-wave-uniform row -> L1 broadcast.
    #pragma unroll
    for (int i = 0; i < 4; ++i) {
        const int s = tid + i * 256;
        const int b = s >> 7, h = s & 127;
        const float* w3r = W3 + (size_t)h * 112;
        const float* rr = rep + ((size_t)z * 64 + bg * 8 + b) * 240;
        float a0 = 0.f, a1 = 0.f, a2 = 0.f, a3 = 0.f, a4 = 0.f,
              a5 = 0.f, a6 = 0.f, a7 = 0.f, a8 = 0.f;
        #pragma unroll 4
        for (int m4 = 0; m4 < 16; ++m4) {            // l=0
            float4 w = *reinterpret_cast<const float4*>(w3r + m4 * 4);
            const float* wp = reinterpret_cast<const float*>(&w);
            #pragma unroll
            for (int c = 0; c < 4; ++c) a0 = fmaf(wp[c], rr[m4 * 4 + c], a0);
        }
        #pragma unroll 2
        for (int u4 = 0; u4 < 8; ++u4) {             // l=1
            float4 w = *reinterpret_cast<const float4*>(w3r + 64 + u4 * 4);
            const float* wp = reinterpret_cast<const float*>(&w);
            #pragma unroll
            for (int c = 0; c < 4; ++c) {
                int u = u4 * 4 + c;
                a1 = fmaf(wp[c], rr[64 + 3 * u + 0], a1);
                a2 = fmaf(wp[c], rr[64 + 3 * u + 1], a2);
                a3 = fmaf(wp[c], rr[64 + 3 * u + 2], a3);
            }
        }
        #pragma unroll 2
        for (int u4 = 0; u4 < 4; ++u4) {             // l=2
            float4 w = *reinterpret_cast<const float4*>(w3r + 96 + u4 * 4);
            const float* wp = reinterpret_cast<const float*>(&w);
            #pragma unroll
            for (int c = 0; c < 4; ++c) {
                int u = u4 * 4 + c;
                a4 = fmaf(wp[c], rr[160 + 5 * u + 0], a4);
                a5 = fmaf(wp[c], rr[160 + 5 * u + 1], a5);
                a6 = fmaf(wp[c], rr[160 + 5 * u + 2], a6);
                a7 = fmaf(wp[c], rr[160 + 5 * u + 3], a7);
                a8 = fmaf(wp[c], rr[160 + 5 * u + 4], a8);
            }
        }
        const float n0 = NORM0 * INV_SQRT_H, n1 = NORM1 * INV_SQRT_H, n2 = NORM2 * INV_SQRT_H;
        float vals[9];
        vals[0] = a0 * n0;
        vals[1] = a1 * n1; vals[2] = a2 * n1; vals[3] = a3 * n1;
        vals[4] = a4 * n2; vals[5] = a5 * n2; vals[6] = a6 * n2;
        vals[7] = a7 * n2; vals[8] = a8 * n2;
        // h = kt*32 + qd*8 + j ; frag pos = (b*4+kt)*512 + (qd*16+n)*8 + j
        const int kt = h >> 5, qd = (h >> 3) & 3, j = h & 7;
        _Float16* base = sVf + (b * 4 + kt) * 512 + qd * 128 + j;
        #pragma unroll
        for (int n = 0; n < 16; ++n)
            base[n * 8] = (n < 9) ? (_Float16)vals[n] : (_Float16)0.0f;
    }
    __syncthreads();   // sVf + sPos* ready

    // ---- main loop ----
    const int aLoc = wv * 16 + m;
    const float ax = sPosA[aLoc * 3 + 0];
    const float ay = sPosA[aLoc * 3 + 1];
    const float az = sPosA[aLoc * 3 + 2];
    float outAcc[4] = {0.f, 0.f, 0.f, 0.f};

    for (int pass = 0; pass < 4; ++pass) {
        const float* w1p0[2];
        const float* w1p1[2];
        float c0v[2], c1v[2];

        #pragma unroll
        for (int p = 0; p < 2; ++p) {
            const int bl = pass * 2 + p;
            const float bx = sPosB[bl * 3 + 0];
            const float by = sPosB[bl * 3 + 1];
            const float bz = sPosB[bl * 3 + 2];
            const float dx = ax - bx, dy = ay - by, dz = az - bz;
            const float r2 = dx * dx + dy * dy + dz * dz;
            const float r = sqrtf(fmaxf(r2, 1e-12f));
            const float u = r * INV_STEP;
            int i0 = (int)floorf(u);
            const float d0 = u - (float)i0;
            float c0 = (i0 >= 0 && i0 < NB_) ? __cosf(HALF_PI * d0) : 0.f;
            const int i1 = i0 + 1;
            const float d1 = d0 - 1.0f;
            float c1 = (i1 >= 0 && i1 < NB_ && d1 > -1.0f) ? __cosf(HALF_PI * d1) : 0.f;
            const int i0c = min(max(i0, 0), NB_ - 1);
            const int i1c = min(max(i1, 0), NB_ - 1);
            w1p0[p] = W1 + i0c * H_;
            w1p1[p] = W1 + i1c * H_;
            c0v[p] = c0 * INV_SQRT_NB;
            c1v[p] = c1 * INV_SQRT_NB;
        }

        f32x4 acc[2][8];
        #pragma unroll
        for (int p = 0; p < 2; ++p)
            #pragma unroll
            for (int nt = 0; nt < 8; ++nt) {
                acc[p][nt][0] = 0.f; acc[p][nt][1] = 0.f;
                acc[p][nt][2] = 0.f; acc[p][nt][3] = 0.f;
            }

        // ---- layer1 (fp16 A-frag regs) + layer2 fp16 MFMA (W2 frags via L1) ----
        #pragma unroll
        for (int kt = 0; kt < 4; ++kt) {
            const int koff = kt * 32 + quad * 8;
            half8 ah[2];
            #pragma unroll
            for (int p = 0; p < 2; ++p) {
                float4 wa0 = *reinterpret_cast<const float4*>(w1p0[p] + koff);
                float4 wa1 = *reinterpret_cast<const float4*>(w1p0[p] + koff + 4);
                float4 wb0 = *reinterpret_cast<const float4*>(w1p1[p] + koff);
                float4 wb1 = *reinterpret_cast<const float4*>(w1p1[p] + koff + 4);
                const float* a0p = reinterpret_cast<const float*>(&wa0);
                const float* a1p = reinterpret_cast<const float*>(&wa1);
                const float* b0p = reinterpret_cast<const float*>(&wb0);
                const float* b1p = reinterpret_cast<const float*>(&wb1);
                #pragma unroll
                for (int j = 0; j < 8; ++j) {
                    float w0 = (j < 4) ? a0p[j] : a1p[j - 4];
                    float w1v = (j < 4) ? b0p[j] : b1p[j - 4];
                    ah[p][j] = (_Float16)ssp_f(fmaf(c0v[p], w0, c1v[p] * w1v));
                }
            }
            const _Float16* bhp = w2f + (size_t)(kt * 8) * 512 + (size_t)lane * 8;
            #pragma unroll
            for (int nt = 0; nt < 8; ++nt) {
                half8 bh = *reinterpret_cast<const half8*>(bhp + nt * 512);
                acc[0][nt] = __builtin_amdgcn_mfma_f32_16x16x32_f16(ah[0], bh, acc[0][nt], 0, 0, 0);
                acc[1][nt] = __builtin_amdgcn_mfma_f32_16x16x32_f16(ah[1], bh, acc[1][nt], 0, 0, 0);
            }
        }

        // ---- per-b epilogue ----
        #pragma unroll
        for (int p = 0; p < 2; ++p) {
            const int bl = pass * 2 + p;

            // Y for this p (recomputed; quad==0 lanes own row m)
            if (quad == 0) {
                const float bx = sPosB[bl * 3 + 0];
                const float by = sPosB[bl * 3 + 1];
                const float bz = sPosB[bl * 3 + 2];
                const float dx = ax - bx, dy = ay - by, dz = az - bz;
                const float r2 = dx * dx + dy * dy + dz * dz;
                const float nzf = (r2 > 1e-10f) ? 1.0f : 0.0f;
                const float ir = rsqrtf(fmaxf(r2, 1e-12f));
                const float x = dx * ir, y = dy * ir, zz = dz * ir;
                float4 g0, g1;
                g0.x = S3 * x * nzf; g0.y = S3 * y * nzf; g0.z = S3 * zz * nzf;
                g0.w = S15 * x * y * nzf;
                g1.x = S15 * y * zz * nzf;
                g1.y = 0.5f * S5 * (3.0f * zz * zz - 1.0f) * nzf;
                g1.z = S15 * x * zz * nzf;
                g1.w = 0.5f * S15 * (x * x - y * y) * nzf;
                *reinterpret_cast<float4*>(&sYw[wv][m][0]) = g0;
                *reinterpret_cast<float4*>(&sYw[wv][m][4]) = g1;
            }

            // ssp + per-kt fp16 transpose through wave-private LDS, then combine
            f32x4 T0 = {0.f, 0.f, 0.f, 0.f};
            f32x4 T1 = {0.f, 0.f, 0.f, 0.f};
            #pragma unroll
            for (int kt = 0; kt < 4; ++kt) {
                #pragma unroll
                for (int ntl = 0; ntl < 2; ++ntl)
                    #pragma unroll
                    for (int reg = 0; reg < 4; ++reg)
                        sH2t[wv][quad * 4 + reg][ntl * 16 + m] =
                            (_Float16)ssp_f(acc[p][kt * 2 + ntl][reg] * INV_SQRT_H);
                half8 ah2 = *reinterpret_cast<const half8*>(&sH2t[wv][m][quad * 8]);
                half8 bv = *reinterpret_cast<const half8*>(sVf + (bl * 4 + kt) * 512 + lane * 8);
                if (kt & 1) T1 = __builtin_amdgcn_mfma_f32_16x16x32_f16(ah2, bv, T1, 0, 0, 0);
                else        T0 = __builtin_amdgcn_mfma_f32_16x16x32_f16(ah2, bv, T0, 0, 0, 0);
            }

            // G-weight (T C-layout: col=lane&15=cm, row=quad*4+reg=a-local)
            const int comp = (m >= 1 && m <= 8) ? (m - 1) : 0;
            float ps[4];
            #pragma unroll
            for (int reg = 0; reg < 4; ++reg) {
                const int row = quad * 4 + reg;
                const float Tv = T0[reg] + T1[reg];
                const float yv = sYw[wv][row][comp];
                const float g = (m == 0) ? 1.0f : ((m <= 8) ? yv : 0.0f);
                ps[reg] = Tv * g;
            }
            #pragma unroll
            for (int off = 1; off < 16; off <<= 1)
                #pragma unroll
                for (int reg = 0; reg < 4; ++reg)
                    ps[reg] += __shfl_xor(ps[reg], off);
            #pragma unroll
            for (int reg = 0; reg < 4; ++reg) outAcc[reg] += ps[reg];
        }
    }

    // ---- write partial[z][bg][a]: lanes m==0 hold a = wv*16 + quad*4 + reg ----
    if (m == 0) {
        float4 st;
        st.x = outAcc[0]; st.y = outAcc[1]; st.z = outAcc[2]; st.w = outAcc[3];
        *reinterpret_cast<float4*>(partial + ((size_t)(z * 8 + bg)) * 64 + wv * 16 + quad * 4) = st;
    }
}

// ---------------------------------------------------------------------------
// finalize: out[z,a] = sp( (sum_bg partial) / sqrt(n_atoms) ) * mask
// ---------------------------------------------------------------------------
__global__ __launch_bounds__(64, 8)
void finalize(const float* __restrict__ partial, const float* __restrict__ mask,
              float* __restrict__ out) {
    const int z = blockIdx.x, a = threadIdx.x;
    const float mk = mask[z * 64 + a];
    float s = mk;
    #pragma unroll
    for (int off = 32; off > 0; off >>= 1) s += __shfl_xor(s, off);
    const float inv = rsqrtf(s);
    float acc = 0.f;
    #pragma unroll
    for (int bg = 0; bg < 8; ++bg)
        acc += partial[((size_t)(z * 8 + bg)) * 64 + a];
    out[z * 64 + a] = sp_f(acc * inv) * mk;
}

extern "C" void kernel_launch(void* const* d_in, const int* in_sizes, int n_in,
                              void* d_out, int out_size, void* d_ws, size_t ws_size,
                              hipStream_t stream) {
    const float* rep  = (const float*)d_in[0];
    const float* geom = (const float*)d_in[1];
    const float* mask = (const float*)d_in[2];
    const float* W1   = (const float*)d_in[3];
    const float* W2   = (const float*)d_in[4];
    const float* W3   = (const float*)d_in[5];
    float* out = (float*)d_out;

    _Float16* w2f = (_Float16*)d_ws;                       // 32768 B
    float* partial = (float*)((char*)d_ws + 32768);        // 512*64*4 = 131072 B

    w2half<<<16, 256, 0, stream>>>(W2, w2f);
    pair4<<<dim3(8, 64), 256, 0, stream>>>(rep, geom, W1, W3, w2f, partial);
    finalize<<<64, 64, 0, stream>>>(partial, mask, out);
}

// Round 2
// 198.221 us; speedup vs baseline: 1.1454x; 1.1454x over previous
//
#include <hip/hip_runtime.h>
#include <math.h>

// B=64, A=64, MULS=((64,0),(32,1),(16,2)) -> DIM_IN=240, NB=32, H=128, MOUT=112
#define H_ 128
#define NB_ 32

#define INV_STEP 3.1f
#define HALF_PI 1.57079632679489662f
#define INV_SQRT_NB 0.17677669529663689f
#define INV_SQRT_H 0.08838834764831845f
#define NORM0 0.125f
#define NORM1 0.10206207261596575f
#define NORM2 0.11180339887498948f
#define S3 1.7320508075688772f
#define S5 2.23606797749979f
#define S15 3.872983346207417f
#define LN2 0.6931471805599453f

typedef __attribute__((ext_vector_type(8))) _Float16 half8;
typedef __attribute__((ext_vector_type(4))) float f32x4;

__device__ __forceinline__ float ssp_f(float x) {
    float t = 5.0f * x;
    float s = fmaxf(t, 0.0f) + __logf(1.0f + __expf(-fabsf(t)));
    return (s - LN2) * 0.2f;
}
__device__ __forceinline__ float sp_f(float x) {
    float t = 5.0f * x;
    float s = fmaxf(t, 0.0f) + __logf(1.0f + __expf(-fabsf(t)));
    return s * 0.2f;
}

// ---------------------------------------------------------------------------
// w2half: W2 (fp32 row-major) -> fp16 MFMA-B-fragment order in ws.
// pos = ((kt*8+nt)*64 + lane)*8 + j ; k = kt*32+(lane>>4)*8+j ; n = nt*16+(lane&15)
// ---------------------------------------------------------------------------
__global__ void w2half(const float* __restrict__ W2, _Float16* __restrict__ w2f) {
    const int e0 = (blockIdx.x * 256 + threadIdx.x) * 4;
    #pragma unroll
    for (int t = 0; t < 4; ++t) {
        const int pos = e0 + t;
        const int j = pos & 7, lane = (pos >> 3) & 63, fn = pos >> 9;
        const int kt = fn >> 3, nt = fn & 7;
        const int k = kt * 32 + (lane >> 4) * 8 + j;
        const int n = nt * 16 + (lane & 15);
        w2f[pos] = (_Float16)W2[k * 128 + n];
    }
}

// ---------------------------------------------------------------------------
// pair4: one block per (z, 8-b-group).
// Round-2 structure: LDS 40960 B (4 blocks/CU) AND single-b main loop so the
// live register set fits __launch_bounds__(256,4)'s 128-reg unified budget:
//   acc[8] f32x4 = 32 acc regs (was acc[2][8] = 64 -> round-1 spilled 343 MB
//   of scratch; VGPR_Count=64 + FETCH_SIZE 183MB was the smoking gun).
// w2f B-frags are re-read per b instead of per 2 b's (L1-resident, +2KB/blk).
// ---------------------------------------------------------------------------
__global__ __launch_bounds__(256, 4)
void pair4(const float* __restrict__ rep, const float* __restrict__ geom,
           const float* __restrict__ W1, const float* __restrict__ W3,
           const _Float16* __restrict__ w2f, float* __restrict__ partial) {
    const int bg = blockIdx.x;           // b in [8bg, 8bg+8)
    const int z  = blockIdx.y;
    const int tid = threadIdx.x;
    const int wv = tid >> 6, lane = tid & 63;
    const int m = lane & 15, quad = lane >> 4;

    __shared__ __align__(16) _Float16 sVf[16384];      // 32768 B  [b][kt][lane][j]
    __shared__ __align__(16) _Float16 sH2t[4][16][40]; // 5120 B   per-wave [a][h2local+pad]
    __shared__ float sYw[4][16][8];                    // 2048 B
    __shared__ float sPosA[192];                       // 768 B
    __shared__ float sPosB[24];                        // 96 B
    // total 40800 B -> 40960 rounded -> 4 blocks/CU exactly

    // ---- startup: stage geom ----
    if (tid < 192) sPosA[tid] = geom[z * 192 + tid];
    else if (tid < 216) sPosB[tid - 192] = geom[((size_t)z * 64 + bg * 8) * 3 + (tid - 192)];

    // ---- V compute: 1024 slots (b,h); emit fp16 B-frags (16 n's incl. zeros) ----
    // rep rows read from global: wave-uniform address -> broadcast, L1/L2-hit.
    #pragma unroll
    for (int i = 0; i < 4; ++i) {
        const int s = tid + i * 256;
        const int b = s >> 7, h = s & 127;
        const float* w3r = W3 + (size_t)h * 112;
        const float* rr = rep + ((size_t)z * 64 + bg * 8 + b) * 240;
        float a0 = 0.f, a1 = 0.f, a2 = 0.f, a3 = 0.f, a4 = 0.f,
              a5 = 0.f, a6 = 0.f, a7 = 0.f, a8 = 0.f;
        #pragma unroll 4
        for (int m4 = 0; m4 < 16; ++m4) {            // l=0
            float4 w = *reinterpret_cast<const float4*>(w3r + m4 * 4);
            const float* wp = reinterpret_cast<const float*>(&w);
            #pragma unroll
            for (int c = 0; c < 4; ++c) a0 = fmaf(wp[c], rr[m4 * 4 + c], a0);
        }
        #pragma unroll 2
        for (int u4 = 0; u4 < 8; ++u4) {             // l=1
            float4 w = *reinterpret_cast<const float4*>(w3r + 64 + u4 * 4);
            const float* wp = reinterpret_cast<const float*>(&w);
            #pragma unroll
            for (int c = 0; c < 4; ++c) {
                int u = u4 * 4 + c;
                a1 = fmaf(wp[c], rr[64 + 3 * u + 0], a1);
                a2 = fmaf(wp[c], rr[64 + 3 * u + 1], a2);
                a3 = fmaf(wp[c], rr[64 + 3 * u + 2], a3);
            }
        }
        #pragma unroll 2
        for (int u4 = 0; u4 < 4; ++u4) {             // l=2
            float4 w = *reinterpret_cast<const float4*>(w3r + 96 + u4 * 4);
            const float* wp = reinterpret_cast<const float*>(&w);
            #pragma unroll
            for (int c = 0; c < 4; ++c) {
                int u = u4 * 4 + c;
                a4 = fmaf(wp[c], rr[160 + 5 * u + 0], a4);
                a5 = fmaf(wp[c], rr[160 + 5 * u + 1], a5);
                a6 = fmaf(wp[c], rr[160 + 5 * u + 2], a6);
                a7 = fmaf(wp[c], rr[160 + 5 * u + 3], a7);
                a8 = fmaf(wp[c], rr[160 + 5 * u + 4], a8);
            }
        }
        const float n0 = NORM0 * INV_SQRT_H, n1 = NORM1 * INV_SQRT_H, n2 = NORM2 * INV_SQRT_H;
        float vals[9];
        vals[0] = a0 * n0;
        vals[1] = a1 * n1; vals[2] = a2 * n1; vals[3] = a3 * n1;
        vals[4] = a4 * n2; vals[5] = a5 * n2; vals[6] = a6 * n2;
        vals[7] = a7 * n2; vals[8] = a8 * n2;
        // h = kt*32 + qd*8 + j ; frag pos = (b*4+kt)*512 + (qd*16+n)*8 + j
        const int kt = h >> 5, qd = (h >> 3) & 3, j = h & 7;
        _Float16* base = sVf + (b * 4 + kt) * 512 + qd * 128 + j;
        #pragma unroll
        for (int n = 0; n < 16; ++n)
            base[n * 8] = (n < 9) ? (_Float16)vals[n] : (_Float16)0.0f;
    }
    __syncthreads();   // sVf + sPos* ready

    // ---- main loop: one b per iteration (register-budget-driven) ----
    const int aLoc = wv * 16 + m;
    const float ax = sPosA[aLoc * 3 + 0];
    const float ay = sPosA[aLoc * 3 + 1];
    const float az = sPosA[aLoc * 3 + 2];
    float outAcc[4] = {0.f, 0.f, 0.f, 0.f};

    for (int bl = 0; bl < 8; ++bl) {
        const float bx = sPosB[bl * 3 + 0];
        const float by = sPosB[bl * 3 + 1];
        const float bz = sPosB[bl * 3 + 2];
        const float dx = ax - bx, dy = ay - by, dz = az - bz;
        const float r2 = dx * dx + dy * dy + dz * dz;

        // radial basis coefficients + W1 row pointers
        const float r = sqrtf(fmaxf(r2, 1e-12f));
        const float u = r * INV_STEP;
        int i0 = (int)floorf(u);
        const float d0 = u - (float)i0;
        float c0 = (i0 >= 0 && i0 < NB_) ? __cosf(HALF_PI * d0) : 0.f;
        const int i1 = i0 + 1;
        const float d1 = d0 - 1.0f;
        float c1 = (i1 >= 0 && i1 < NB_ && d1 > -1.0f) ? __cosf(HALF_PI * d1) : 0.f;
        const int i0c = min(max(i0, 0), NB_ - 1);
        const int i1c = min(max(i1, 0), NB_ - 1);
        const float* w1p0 = W1 + i0c * H_;
        const float* w1p1 = W1 + i1c * H_;
        const float c0v = c0 * INV_SQRT_NB;
        const float c1v = c1 * INV_SQRT_NB;

        // Y for this b (quad==0 lanes own a-row m); wave-private, no barrier
        if (quad == 0) {
            const float nzf = (r2 > 1e-10f) ? 1.0f : 0.0f;
            const float ir = rsqrtf(fmaxf(r2, 1e-12f));
            const float x = dx * ir, y = dy * ir, zz = dz * ir;
            float4 g0, g1;
            g0.x = S3 * x * nzf; g0.y = S3 * y * nzf; g0.z = S3 * zz * nzf;
            g0.w = S15 * x * y * nzf;
            g1.x = S15 * y * zz * nzf;
            g1.y = 0.5f * S5 * (3.0f * zz * zz - 1.0f) * nzf;
            g1.z = S15 * x * zz * nzf;
            g1.w = 0.5f * S15 * (x * x - y * y) * nzf;
            *reinterpret_cast<float4*>(&sYw[wv][m][0]) = g0;
            *reinterpret_cast<float4*>(&sYw[wv][m][4]) = g1;
        }

        f32x4 acc[8];
        #pragma unroll
        for (int nt = 0; nt < 8; ++nt) {
            acc[nt][0] = 0.f; acc[nt][1] = 0.f;
            acc[nt][2] = 0.f; acc[nt][3] = 0.f;
        }

        // ---- layer1 (fp16 A-frag regs) + layer2 fp16 MFMA ----
        #pragma unroll
        for (int kt = 0; kt < 4; ++kt) {
            const int koff = kt * 32 + quad * 8;
            float4 wa0 = *reinterpret_cast<const float4*>(w1p0 + koff);
            float4 wa1 = *reinterpret_cast<const float4*>(w1p0 + koff + 4);
            float4 wb0 = *reinterpret_cast<const float4*>(w1p1 + koff);
            float4 wb1 = *reinterpret_cast<const float4*>(w1p1 + koff + 4);
            const float* a0p = reinterpret_cast<const float*>(&wa0);
            const float* a1p = reinterpret_cast<const float*>(&wa1);
            const float* b0p = reinterpret_cast<const float*>(&wb0);
            const float* b1p = reinterpret_cast<const float*>(&wb1);
            half8 ah;
            #pragma unroll
            for (int j = 0; j < 8; ++j) {
                float w0 = (j < 4) ? a0p[j] : a1p[j - 4];
                float w1v = (j < 4) ? b0p[j] : b1p[j - 4];
                ah[j] = (_Float16)ssp_f(fmaf(c0v, w0, c1v * w1v));
            }
            const _Float16* bhp = w2f + (size_t)(kt * 8) * 512 + (size_t)lane * 8;
            #pragma unroll
            for (int nt = 0; nt < 8; ++nt) {
                half8 bh = *reinterpret_cast<const half8*>(bhp + nt * 512);
                acc[nt] = __builtin_amdgcn_mfma_f32_16x16x32_f16(ah, bh, acc[nt], 0, 0, 0);
            }
        }

        // ---- epilogue: ssp + per-kt fp16 transpose, combine vs V frags ----
        f32x4 T0 = {0.f, 0.f, 0.f, 0.f};
        f32x4 T1 = {0.f, 0.f, 0.f, 0.f};
        #pragma unroll
        for (int kt = 0; kt < 4; ++kt) {
            #pragma unroll
            for (int ntl = 0; ntl < 2; ++ntl)
                #pragma unroll
                for (int reg = 0; reg < 4; ++reg)
                    sH2t[wv][quad * 4 + reg][ntl * 16 + m] =
                        (_Float16)ssp_f(acc[kt * 2 + ntl][reg] * INV_SQRT_H);
            half8 ah2 = *reinterpret_cast<const half8*>(&sH2t[wv][m][quad * 8]);
            half8 bv = *reinterpret_cast<const half8*>(sVf + (bl * 4 + kt) * 512 + lane * 8);
            if (kt & 1) T1 = __builtin_amdgcn_mfma_f32_16x16x32_f16(ah2, bv, T1, 0, 0, 0);
            else        T0 = __builtin_amdgcn_mfma_f32_16x16x32_f16(ah2, bv, T0, 0, 0, 0);
        }

        // G-weight (T C-layout: col=lane&15=cm, row=quad*4+reg=a-local)
        const int comp = (m >= 1 && m <= 8) ? (m - 1) : 0;
        float ps[4];
        #pragma unroll
        for (int reg = 0; reg < 4; ++reg) {
            const int row = quad * 4 + reg;
            const float Tv = T0[reg] + T1[reg];
            const float yv = sYw[wv][row][comp];
            const float g = (m == 0) ? 1.0f : ((m <= 8) ? yv : 0.0f);
            ps[reg] = Tv * g;
        }
        #pragma unroll
        for (int off = 1; off < 16; off <<= 1)
            #pragma unroll
            for (int reg = 0; reg < 4; ++reg)
                ps[reg] += __shfl_xor(ps[reg], off);
        #pragma unroll
        for (int reg = 0; reg < 4; ++reg) outAcc[reg] += ps[reg];
    }

    // ---- write partial[z][bg][a]: lanes m==0 hold a = wv*16 + quad*4 + reg ----
    if (m == 0) {
        float4 st;
        st.x = outAcc[0]; st.y = outAcc[1]; st.z = outAcc[2]; st.w = outAcc[3];
        *reinterpret_cast<float4*>(partial + ((size_t)(z * 8 + bg)) * 64 + wv * 16 + quad * 4) = st;
    }
}

// ---------------------------------------------------------------------------
// finalize: out[z,a] = sp( (sum_bg partial) / sqrt(n_atoms) ) * mask
// ---------------------------------------------------------------------------
__global__ __launch_bounds__(64, 8)
void finalize(const float* __restrict__ partial, const float* __restrict__ mask,
              float* __restrict__ out) {
    const int z = blockIdx.x, a = threadIdx.x;
    const float mk = mask[z * 64 + a];
    float s = mk;
    #pragma unroll
    for (int off = 32; off > 0; off >>= 1) s += __shfl_xor(s, off);
    const float inv = rsqrtf(s);
    float acc = 0.f;
    #pragma unroll
    for (int bg = 0; bg < 8; ++bg)
        acc += partial[((size_t)(z * 8 + bg)) * 64 + a];
    out[z * 64 + a] = sp_f(acc * inv) * mk;
}

extern "C" void kernel_launch(void* const* d_in, const int* in_sizes, int n_in,
                              void* d_out, int out_size, void* d_ws, size_t ws_size,
                              hipStream_t stream) {
    const float* rep  = (const float*)d_in[0];
    const float* geom = (const float*)d_in[1];
    const float* mask = (const float*)d_in[2];
    const float* W1   = (const float*)d_in[3];
    const float* W2   = (const float*)d_in[4];
    const float* W3   = (const float*)d_in[5];
    float* out = (float*)d_out;

    _Float16* w2f = (_Float16*)d_ws;                       // 32768 B
    float* partial = (float*)((char*)d_ws + 32768);        // 512*64*4 = 131072 B

    w2half<<<16, 256, 0, stream>>>(W2, w2f);
    pair4<<<dim3(8, 64), 256, 0, stream>>>(rep, geom, W1, W3, w2f, partial);
    finalize<<<64, 64, 0, stream>>>(partial, mask, out);
}

// Round 3
// 165.252 us; speedup vs baseline: 1.3740x; 1.1995x over previous
//
#include <hip/hip_runtime.h>
#include <math.h>

// B=64, A=64, MULS=((64,0),(32,1),(16,2)) -> DIM_IN=240, NB=32, H=128, MOUT=112
#define H_ 128
#define NB_ 32

#define INV_STEP 3.1f
#define HALF_PI 1.57079632679489662f
#define INV_SQRT_NB 0.17677669529663689f
#define INV_SQRT_H 0.08838834764831845f
#define NORM0 0.125f
#define NORM1 0.10206207261596575f
#define NORM2 0.11180339887498948f
#define S3 1.7320508075688772f
#define S5 2.23606797749979f
#define S15 3.872983346207417f
#define LN2 0.6931471805599453f

typedef __attribute__((ext_vector_type(8))) _Float16 half8;
typedef __attribute__((ext_vector_type(4))) float f32x4;

__device__ __forceinline__ float ssp_f(float x) {
    float t = 5.0f * x;
    float s = fmaxf(t, 0.0f) + __logf(1.0f + __expf(-fabsf(t)));
    return (s - LN2) * 0.2f;
}
__device__ __forceinline__ float sp_f(float x) {
    float t = 5.0f * x;
    float s = fmaxf(t, 0.0f) + __logf(1.0f + __expf(-fabsf(t)));
    return s * 0.2f;
}

// ---------------------------------------------------------------------------
// w2half: W2 (fp32 row-major) -> fp16 MFMA-B-fragment order in ws.
// pos = ((kt*8+nt)*64 + lane)*8 + j ; k = kt*32+(lane>>4)*8+j ; n = nt*16+(lane&15)
// ---------------------------------------------------------------------------
__global__ void w2half(const float* __restrict__ W2, _Float16* __restrict__ w2f) {
    const int e0 = (blockIdx.x * 256 + threadIdx.x) * 4;
    #pragma unroll
    for (int t = 0; t < 4; ++t) {
        const int pos = e0 + t;
        const int j = pos & 7, lane = (pos >> 3) & 63, fn = pos >> 9;
        const int kt = fn >> 3, nt = fn & 7;
        const int k = kt * 32 + (lane >> 4) * 8 + j;
        const int n = nt * 16 + (lane & 15);
        w2f[pos] = (_Float16)W2[k * 128 + n];
    }
}

// ---------------------------------------------------------------------------
// pair4: one block per (z, 8-b-group).
// Round-3: LDS 40960 B + single-b loop + __launch_bounds__(256,3):
//   - (256,4)'s 128-reg unified budget was unaffordable (rounds 1-2 spilled
//     100-340 MB of scratch; VGPR_Count=64 was the signature). The 3-wave/SIMD
//     step gives ~170 regs; single-b live set (~140-150) fits.
//   - #pragma unroll 1 on the bl loop: the compiler fully unrolled the
//     8-iteration loop in rounds 1-2, stretching live ranges across b's
//     (spill volume ~1.1 KB/thread = unroll bloat, not marginal overflow).
//   - Occupancy: 3 blocks/CU (LDS allows 4, regs allow 3) = 12 waves/CU,
//     vs round-0's 2 blocks at 72 KB LDS.
// ---------------------------------------------------------------------------
__global__ __launch_bounds__(256, 3)
void pair4(const float* __restrict__ rep, const float* __restrict__ geom,
           const float* __restrict__ W1, const float* __restrict__ W3,
           const _Float16* __restrict__ w2f, float* __restrict__ partial) {
    const int bg = blockIdx.x;           // b in [8bg, 8bg+8)
    const int z  = blockIdx.y;
    const int tid = threadIdx.x;
    const int wv = tid >> 6, lane = tid & 63;
    const int m = lane & 15, quad = lane >> 4;

    __shared__ __align__(16) _Float16 sVf[16384];      // 32768 B  [b][kt][lane][j]
    __shared__ __align__(16) _Float16 sH2t[4][16][40]; // 5120 B   per-wave [a][h2local+pad]
    __shared__ float sYw[4][16][8];                    // 2048 B
    __shared__ float sPosA[192];                       // 768 B
    __shared__ float sPosB[24];                        // 96 B
    // total 40800 B -> 40960 rounded

    // ---- startup: stage geom ----
    if (tid < 192) sPosA[tid] = geom[z * 192 + tid];
    else if (tid < 216) sPosB[tid - 192] = geom[((size_t)z * 64 + bg * 8) * 3 + (tid - 192)];

    // ---- V compute: 1024 slots (b,h); emit fp16 B-frags (16 n's incl. zeros) ----
    // rep rows read from global: wave-uniform address -> broadcast, L1/L2-hit.
    #pragma unroll
    for (int i = 0; i < 4; ++i) {
        const int s = tid + i * 256;
        const int b = s >> 7, h = s & 127;
        const float* w3r = W3 + (size_t)h * 112;
        const float* rr = rep + ((size_t)z * 64 + bg * 8 + b) * 240;
        float a0 = 0.f, a1 = 0.f, a2 = 0.f, a3 = 0.f, a4 = 0.f,
              a5 = 0.f, a6 = 0.f, a7 = 0.f, a8 = 0.f;
        #pragma unroll 4
        for (int m4 = 0; m4 < 16; ++m4) {            // l=0
            float4 w = *reinterpret_cast<const float4*>(w3r + m4 * 4);
            const float* wp = reinterpret_cast<const float*>(&w);
            #pragma unroll
            for (int c = 0; c < 4; ++c) a0 = fmaf(wp[c], rr[m4 * 4 + c], a0);
        }
        #pragma unroll 2
        for (int u4 = 0; u4 < 8; ++u4) {             // l=1
            float4 w = *reinterpret_cast<const float4*>(w3r + 64 + u4 * 4);
            const float* wp = reinterpret_cast<const float*>(&w);
            #pragma unroll
            for (int c = 0; c < 4; ++c) {
                int u = u4 * 4 + c;
                a1 = fmaf(wp[c], rr[64 + 3 * u + 0], a1);
                a2 = fmaf(wp[c], rr[64 + 3 * u + 1], a2);
                a3 = fmaf(wp[c], rr[64 + 3 * u + 2], a3);
            }
        }
        #pragma unroll 2
        for (int u4 = 0; u4 < 4; ++u4) {             // l=2
            float4 w = *reinterpret_cast<const float4*>(w3r + 96 + u4 * 4);
            const float* wp = reinterpret_cast<const float*>(&w);
            #pragma unroll
            for (int c = 0; c < 4; ++c) {
                int u = u4 * 4 + c;
                a4 = fmaf(wp[c], rr[160 + 5 * u + 0], a4);
                a5 = fmaf(wp[c], rr[160 + 5 * u + 1], a5);
                a6 = fmaf(wp[c], rr[160 + 5 * u + 2], a6);
                a7 = fmaf(wp[c], rr[160 + 5 * u + 3], a7);
                a8 = fmaf(wp[c], rr[160 + 5 * u + 4], a8);
            }
        }
        const float n0 = NORM0 * INV_SQRT_H, n1 = NORM1 * INV_SQRT_H, n2 = NORM2 * INV_SQRT_H;
        float vals[9];
        vals[0] = a0 * n0;
        vals[1] = a1 * n1; vals[2] = a2 * n1; vals[3] = a3 * n1;
        vals[4] = a4 * n2; vals[5] = a5 * n2; vals[6] = a6 * n2;
        vals[7] = a7 * n2; vals[8] = a8 * n2;
        // h = kt*32 + qd*8 + j ; frag pos = (b*4+kt)*512 + (qd*16+n)*8 + j
        const int kt = h >> 5, qd = (h >> 3) & 3, j = h & 7;
        _Float16* base = sVf + (b * 4 + kt) * 512 + qd * 128 + j;
        #pragma unroll
        for (int n = 0; n < 16; ++n)
            base[n * 8] = (n < 9) ? (_Float16)vals[n] : (_Float16)0.0f;
    }
    __syncthreads();   // sVf + sPos* ready

    // ---- main loop: one b per iteration, NOT unrolled (register budget) ----
    const int aLoc = wv * 16 + m;
    const float ax = sPosA[aLoc * 3 + 0];
    const float ay = sPosA[aLoc * 3 + 1];
    const float az = sPosA[aLoc * 3 + 2];
    float outAcc[4] = {0.f, 0.f, 0.f, 0.f};

    #pragma unroll 1
    for (int bl = 0; bl < 8; ++bl) {
        const float bx = sPosB[bl * 3 + 0];
        const float by = sPosB[bl * 3 + 1];
        const float bz = sPosB[bl * 3 + 2];
        const float dx = ax - bx, dy = ay - by, dz = az - bz;
        const float r2 = dx * dx + dy * dy + dz * dz;

        // radial basis coefficients + W1 row pointers
        const float r = sqrtf(fmaxf(r2, 1e-12f));
        const float u = r * INV_STEP;
        int i0 = (int)floorf(u);
        const float d0 = u - (float)i0;
        float c0 = (i0 >= 0 && i0 < NB_) ? __cosf(HALF_PI * d0) : 0.f;
        const int i1 = i0 + 1;
        const float d1 = d0 - 1.0f;
        float c1 = (i1 >= 0 && i1 < NB_ && d1 > -1.0f) ? __cosf(HALF_PI * d1) : 0.f;
        const int i0c = min(max(i0, 0), NB_ - 1);
        const int i1c = min(max(i1, 0), NB_ - 1);
        const float* w1p0 = W1 + i0c * H_;
        const float* w1p1 = W1 + i1c * H_;
        const float c0v = c0 * INV_SQRT_NB;
        const float c1v = c1 * INV_SQRT_NB;

        // Y for this b (quad==0 lanes own a-row m); wave-private, no barrier
        if (quad == 0) {
            const float nzf = (r2 > 1e-10f) ? 1.0f : 0.0f;
            const float ir = rsqrtf(fmaxf(r2, 1e-12f));
            const float x = dx * ir, y = dy * ir, zz = dz * ir;
            float4 g0, g1;
            g0.x = S3 * x * nzf; g0.y = S3 * y * nzf; g0.z = S3 * zz * nzf;
            g0.w = S15 * x * y * nzf;
            g1.x = S15 * y * zz * nzf;
            g1.y = 0.5f * S5 * (3.0f * zz * zz - 1.0f) * nzf;
            g1.z = S15 * x * zz * nzf;
            g1.w = 0.5f * S15 * (x * x - y * y) * nzf;
            *reinterpret_cast<float4*>(&sYw[wv][m][0]) = g0;
            *reinterpret_cast<float4*>(&sYw[wv][m][4]) = g1;
        }

        f32x4 acc[8];
        #pragma unroll
        for (int nt = 0; nt < 8; ++nt) {
            acc[nt][0] = 0.f; acc[nt][1] = 0.f;
            acc[nt][2] = 0.f; acc[nt][3] = 0.f;
        }

        // ---- layer1 (fp16 A-frag regs) + layer2 fp16 MFMA ----
        #pragma unroll
        for (int kt = 0; kt < 4; ++kt) {
            const int koff = kt * 32 + quad * 8;
            float4 wa0 = *reinterpret_cast<const float4*>(w1p0 + koff);
            float4 wa1 = *reinterpret_cast<const float4*>(w1p0 + koff + 4);
            float4 wb0 = *reinterpret_cast<const float4*>(w1p1 + koff);
            float4 wb1 = *reinterpret_cast<const float4*>(w1p1 + koff + 4);
            const float* a0p = reinterpret_cast<const float*>(&wa0);
            const float* a1p = reinterpret_cast<const float*>(&wa1);
            const float* b0p = reinterpret_cast<const float*>(&wb0);
            const float* b1p = reinterpret_cast<const float*>(&wb1);
            half8 ah;
            #pragma unroll
            for (int j = 0; j < 8; ++j) {
                float w0 = (j < 4) ? a0p[j] : a1p[j - 4];
                float w1v = (j < 4) ? b0p[j] : b1p[j - 4];
                ah[j] = (_Float16)ssp_f(fmaf(c0v, w0, c1v * w1v));
            }
            const _Float16* bhp = w2f + (size_t)(kt * 8) * 512 + (size_t)lane * 8;
            #pragma unroll
            for (int nt = 0; nt < 8; ++nt) {
                half8 bh = *reinterpret_cast<const half8*>(bhp + nt * 512);
                acc[nt] = __builtin_amdgcn_mfma_f32_16x16x32_f16(ah, bh, acc[nt], 0, 0, 0);
            }
        }

        // ---- epilogue: ssp + per-kt fp16 transpose, combine vs V frags ----
        f32x4 T0 = {0.f, 0.f, 0.f, 0.f};
        f32x4 T1 = {0.f, 0.f, 0.f, 0.f};
        #pragma unroll
        for (int kt = 0; kt < 4; ++kt) {
            #pragma unroll
            for (int ntl = 0; ntl < 2; ++ntl)
                #pragma unroll
                for (int reg = 0; reg < 4; ++reg)
                    sH2t[wv][quad * 4 + reg][ntl * 16 + m] =
                        (_Float16)ssp_f(acc[kt * 2 + ntl][reg] * INV_SQRT_H);
            half8 ah2 = *reinterpret_cast<const half8*>(&sH2t[wv][m][quad * 8]);
            half8 bv = *reinterpret_cast<const half8*>(sVf + (bl * 4 + kt) * 512 + lane * 8);
            if (kt & 1) T1 = __builtin_amdgcn_mfma_f32_16x16x32_f16(ah2, bv, T1, 0, 0, 0);
            else        T0 = __builtin_amdgcn_mfma_f32_16x16x32_f16(ah2, bv, T0, 0, 0, 0);
        }

        // G-weight (T C-layout: col=lane&15=cm, row=quad*4+reg=a-local)
        const int comp = (m >= 1 && m <= 8) ? (m - 1) : 0;
        float ps[4];
        #pragma unroll
        for (int reg = 0; reg < 4; ++reg) {
            const int row = quad * 4 + reg;
            const float Tv = T0[reg] + T1[reg];
            const float yv = sYw[wv][row][comp];
            const float g = (m == 0) ? 1.0f : ((m <= 8) ? yv : 0.0f);
            ps[reg] = Tv * g;
        }
        #pragma unroll
        for (int off = 1; off < 16; off <<= 1)
            #pragma unroll
            for (int reg = 0; reg < 4; ++reg)
                ps[reg] += __shfl_xor(ps[reg], off);
        #pragma unroll
        for (int reg = 0; reg < 4; ++reg) outAcc[reg] += ps[reg];
    }

    // ---- write partial[z][bg][a]: lanes m==0 hold a = wv*16 + quad*4 + reg ----
    if (m == 0) {
        float4 st;
        st.x = outAcc[0]; st.y = outAcc[1]; st.z = outAcc[2]; st.w = outAcc[3];
        *reinterpret_cast<float4*>(partial + ((size_t)(z * 8 + bg)) * 64 + wv * 16 + quad * 4) = st;
    }
}

// ---------------------------------------------------------------------------
// finalize: out[z,a] = sp( (sum_bg partial) / sqrt(n_atoms) ) * mask
// ---------------------------------------------------------------------------
__global__ __launch_bounds__(64, 8)
void finalize(const float* __restrict__ partial, const float* __restrict__ mask,
              float* __restrict__ out) {
    const int z = blockIdx.x, a = threadIdx.x;
    const float mk = mask[z * 64 + a];
    float s = mk;
    #pragma unroll
    for (int off = 32; off > 0; off >>= 1) s += __shfl_xor(s, off);
    const float inv = rsqrtf(s);
    float acc = 0.f;
    #pragma unroll
    for (int bg = 0; bg < 8; ++bg)
        acc += partial[((size_t)(z * 8 + bg)) * 64 + a];
    out[z * 64 + a] = sp_f(acc * inv) * mk;
}

extern "C" void kernel_launch(void* const* d_in, const int* in_sizes, int n_in,
                              void* d_out, int out_size, void* d_ws, size_t ws_size,
                              hipStream_t stream) {
    const float* rep  = (const float*)d_in[0];
    const float* geom = (const float*)d_in[1];
    const float* mask = (const float*)d_in[2];
    const float* W1   = (const float*)d_in[3];
    const float* W2   = (const float*)d_in[4];
    const float* W3   = (const float*)d_in[5];
    float* out = (float*)d_out;

    _Float16* w2f = (_Float16*)d_ws;                       // 32768 B
    float* partial = (float*)((char*)d_ws + 32768);        // 512*64*4 = 131072 B

    w2half<<<16, 256, 0, stream>>>(W2, w2f);
    pair4<<<dim3(8, 64), 256, 0, stream>>>(rep, geom, W1, W3, w2f, partial);
    finalize<<<64, 64, 0, stream>>>(partial, mask, out);
}

// Round 4
// 153.448 us; speedup vs baseline: 1.4797x; 1.0769x over previous
//
#include <hip/hip_runtime.h>
#include <math.h>

// B=64, A=64, MULS=((64,0),(32,1),(16,2)) -> DIM_IN=240, NB=32, H=128, MOUT=112
#define H_ 128
#define NB_ 32

#define INV_STEP 3.1f
#define HALF_PI 1.57079632679489662f
#define INV_SQRT_NB 0.17677669529663689f
#define INV_SQRT_H 0.08838834764831845f
#define NORM0 0.125f
#define NORM1 0.10206207261596575f
#define NORM2 0.11180339887498948f
#define S3 1.7320508075688772f
#define S5 2.23606797749979f
#define S15 3.872983346207417f
#define LN2 0.6931471805599453f

typedef __attribute__((ext_vector_type(8))) _Float16 half8;
typedef __attribute__((ext_vector_type(4))) float f32x4;

__device__ __forceinline__ float ssp_f(float x) {
    float t = 5.0f * x;
    float s = fmaxf(t, 0.0f) + __logf(1.0f + __expf(-fabsf(t)));
    return (s - LN2) * 0.2f;
}
__device__ __forceinline__ float sp_f(float x) {
    float t = 5.0f * x;
    float s = fmaxf(t, 0.0f) + __logf(1.0f + __expf(-fabsf(t)));
    return s * 0.2f;
}

// ---------------------------------------------------------------------------
// w2half: W2 (fp32 row-major) -> fp16 MFMA-B-fragment order in ws.
// pos = ((kt*8+nt)*64 + lane)*8 + j ; k = kt*32+(lane>>4)*8+j ; n = nt*16+(lane&15)
// ---------------------------------------------------------------------------
__global__ void w2half(const float* __restrict__ W2, _Float16* __restrict__ w2f) {
    const int e0 = (blockIdx.x * 256 + threadIdx.x) * 4;
    #pragma unroll
    for (int t = 0; t < 4; ++t) {
        const int pos = e0 + t;
        const int j = pos & 7, lane = (pos >> 3) & 63, fn = pos >> 9;
        const int kt = fn >> 3, nt = fn & 7;
        const int k = kt * 32 + (lane >> 4) * 8 + j;
        const int n = nt * 16 + (lane & 15);
        w2f[pos] = (_Float16)W2[k * 128 + n];
    }
}

// ---------------------------------------------------------------------------
// pair4: one block per (z, 4-b-group). Round-4 findings applied:
//   - GRID was the occupancy bound: 512 blocks / 256 CU = 2 blocks/CU no
//     matter the LDS/regs. Split bg 8->16 groups of 4 b's: grid 1024 ->
//     4 blocks/CU available; (256,3) regs + 24.4 KB LDS -> 3 resident.
//   - Unified-file even split: MFMA kernels get arch = budget/2 (measured:
//     (256,2)->128, (256,3)->84, (256,4)->64 arch regs). At (256,3) the
//     arch set must fit 84: kt-loop unroll 2 (8 hoisted W1 float4s, not 16)
//     plus bl-loop unroll 1 keeps it ~80. Round-3's 21 MB scratch = the
//     ~30-dword overflow of the fully-unrolled body at this split.
// ---------------------------------------------------------------------------
__global__ __launch_bounds__(256, 3)
void pair4(const float* __restrict__ rep, const float* __restrict__ geom,
           const float* __restrict__ W1, const float* __restrict__ W3,
           const _Float16* __restrict__ w2f, float* __restrict__ partial) {
    const int bg = blockIdx.x;           // b in [4bg, 4bg+4)
    const int z  = blockIdx.y;
    const int tid = threadIdx.x;
    const int wv = tid >> 6, lane = tid & 63;
    const int m = lane & 15, quad = lane >> 4;

    __shared__ __align__(16) _Float16 sVf[8192];       // 16384 B  [b<4][kt][lane][j]
    __shared__ __align__(16) _Float16 sH2t[4][16][40]; // 5120 B   per-wave [a][h2local+pad]
    __shared__ float sYw[4][16][8];                    // 2048 B
    __shared__ float sPosA[192];                       // 768 B
    __shared__ float sPosB[12];                        // 48 B
    // total ~24.4 KB -> 6 blocks/CU by LDS; regs bind at 3

    // ---- startup: stage geom ----
    if (tid < 192) sPosA[tid] = geom[z * 192 + tid];
    else if (tid < 204) sPosB[tid - 192] = geom[((size_t)z * 64 + bg * 4) * 3 + (tid - 192)];

    // ---- V compute: 512 slots (b<4, h<128); emit fp16 B-frags ----
    // rep rows read from global: wave-uniform address -> broadcast, L1/L2-hit.
    #pragma unroll
    for (int i = 0; i < 2; ++i) {
        const int s = tid + i * 256;
        const int b = s >> 7, h = s & 127;
        const float* w3r = W3 + (size_t)h * 112;
        const float* rr = rep + ((size_t)z * 64 + bg * 4 + b) * 240;
        float a0 = 0.f, a1 = 0.f, a2 = 0.f, a3 = 0.f, a4 = 0.f,
              a5 = 0.f, a6 = 0.f, a7 = 0.f, a8 = 0.f;
        #pragma unroll 4
        for (int m4 = 0; m4 < 16; ++m4) {            // l=0
            float4 w = *reinterpret_cast<const float4*>(w3r + m4 * 4);
            const float* wp = reinterpret_cast<const float*>(&w);
            #pragma unroll
            for (int c = 0; c < 4; ++c) a0 = fmaf(wp[c], rr[m4 * 4 + c], a0);
        }
        #pragma unroll 2
        for (int u4 = 0; u4 < 8; ++u4) {             // l=1
            float4 w = *reinterpret_cast<const float4*>(w3r + 64 + u4 * 4);
            const float* wp = reinterpret_cast<const float*>(&w);
            #pragma unroll
            for (int c = 0; c < 4; ++c) {
                int u = u4 * 4 + c;
                a1 = fmaf(wp[c], rr[64 + 3 * u + 0], a1);
                a2 = fmaf(wp[c], rr[64 + 3 * u + 1], a2);
                a3 = fmaf(wp[c], rr[64 + 3 * u + 2], a3);
            }
        }
        #pragma unroll 2
        for (int u4 = 0; u4 < 4; ++u4) {             // l=2
            float4 w = *reinterpret_cast<const float4*>(w3r + 96 + u4 * 4);
            const float* wp = reinterpret_cast<const float*>(&w);
            #pragma unroll
            for (int c = 0; c < 4; ++c) {
                int u = u4 * 4 + c;
                a4 = fmaf(wp[c], rr[160 + 5 * u + 0], a4);
                a5 = fmaf(wp[c], rr[160 + 5 * u + 1], a5);
                a6 = fmaf(wp[c], rr[160 + 5 * u + 2], a6);
                a7 = fmaf(wp[c], rr[160 + 5 * u + 3], a7);
                a8 = fmaf(wp[c], rr[160 + 5 * u + 4], a8);
            }
        }
        const float n0 = NORM0 * INV_SQRT_H, n1 = NORM1 * INV_SQRT_H, n2 = NORM2 * INV_SQRT_H;
        float vals[9];
        vals[0] = a0 * n0;
        vals[1] = a1 * n1; vals[2] = a2 * n1; vals[3] = a3 * n1;
        vals[4] = a4 * n2; vals[5] = a5 * n2; vals[6] = a6 * n2;
        vals[7] = a7 * n2; vals[8] = a8 * n2;
        // h = kt*32 + qd*8 + j ; frag pos = (b*4+kt)*512 + (qd*16+n)*8 + j
        const int kt = h >> 5, qd = (h >> 3) & 3, j = h & 7;
        _Float16* base = sVf + (b * 4 + kt) * 512 + qd * 128 + j;
        #pragma unroll
        for (int n = 0; n < 16; ++n)
            base[n * 8] = (n < 9) ? (_Float16)vals[n] : (_Float16)0.0f;
    }
    __syncthreads();   // sVf + sPos* ready

    // ---- main loop: one b per iteration, NOT unrolled (register budget) ----
    const int aLoc = wv * 16 + m;
    const float ax = sPosA[aLoc * 3 + 0];
    const float ay = sPosA[aLoc * 3 + 1];
    const float az = sPosA[aLoc * 3 + 2];
    float outAcc[4] = {0.f, 0.f, 0.f, 0.f};

    #pragma unroll 1
    for (int bl = 0; bl < 4; ++bl) {
        const float bx = sPosB[bl * 3 + 0];
        const float by = sPosB[bl * 3 + 1];
        const float bz = sPosB[bl * 3 + 2];
        const float dx = ax - bx, dy = ay - by, dz = az - bz;
        const float r2 = dx * dx + dy * dy + dz * dz;

        // radial basis coefficients + W1 row pointers
        const float r = sqrtf(fmaxf(r2, 1e-12f));
        const float u = r * INV_STEP;
        int i0 = (int)floorf(u);
        const float d0 = u - (float)i0;
        float c0 = (i0 >= 0 && i0 < NB_) ? __cosf(HALF_PI * d0) : 0.f;
        const int i1 = i0 + 1;
        const float d1 = d0 - 1.0f;
        float c1 = (i1 >= 0 && i1 < NB_ && d1 > -1.0f) ? __cosf(HALF_PI * d1) : 0.f;
        const int i0c = min(max(i0, 0), NB_ - 1);
        const int i1c = min(max(i1, 0), NB_ - 1);
        const float* w1p0 = W1 + i0c * H_;
        const float* w1p1 = W1 + i1c * H_;
        const float c0v = c0 * INV_SQRT_NB;
        const float c1v = c1 * INV_SQRT_NB;

        // Y for this b (quad==0 lanes own a-row m); wave-private, no barrier
        if (quad == 0) {
            const float nzf = (r2 > 1e-10f) ? 1.0f : 0.0f;
            const float ir = rsqrtf(fmaxf(r2, 1e-12f));
            const float x = dx * ir, y = dy * ir, zz = dz * ir;
            float4 g0, g1;
            g0.x = S3 * x * nzf; g0.y = S3 * y * nzf; g0.z = S3 * zz * nzf;
            g0.w = S15 * x * y * nzf;
            g1.x = S15 * y * zz * nzf;
            g1.y = 0.5f * S5 * (3.0f * zz * zz - 1.0f) * nzf;
            g1.z = S15 * x * zz * nzf;
            g1.w = 0.5f * S15 * (x * x - y * y) * nzf;
            *reinterpret_cast<float4*>(&sYw[wv][m][0]) = g0;
            *reinterpret_cast<float4*>(&sYw[wv][m][4]) = g1;
        }

        f32x4 acc[8];
        #pragma unroll
        for (int nt = 0; nt < 8; ++nt) {
            acc[nt][0] = 0.f; acc[nt][1] = 0.f;
            acc[nt][2] = 0.f; acc[nt][3] = 0.f;
        }

        // ---- layer1 (fp16 A-frag regs) + layer2 fp16 MFMA ----
        // unroll 2 (not 4): caps hoisted W1 float4s at 8 -> arch set fits
        // the 84-reg half-split at (256,3).
        #pragma unroll 2
        for (int kt = 0; kt < 4; ++kt) {
            const int koff = kt * 32 + quad * 8;
            float4 wa0 = *reinterpret_cast<const float4*>(w1p0 + koff);
            float4 wa1 = *reinterpret_cast<const float4*>(w1p0 + koff + 4);
            float4 wb0 = *reinterpret_cast<const float4*>(w1p1 + koff);
            float4 wb1 = *reinterpret_cast<const float4*>(w1p1 + koff + 4);
            const float* a0p = reinterpret_cast<const float*>(&wa0);
            const float* a1p = reinterpret_cast<const float*>(&wa1);
            const float* b0p = reinterpret_cast<const float*>(&wb0);
            const float* b1p = reinterpret_cast<const float*>(&wb1);
            half8 ah;
            #pragma unroll
            for (int j = 0; j < 8; ++j) {
                float w0 = (j < 4) ? a0p[j] : a1p[j - 4];
                float w1v = (j < 4) ? b0p[j] : b1p[j - 4];
                ah[j] = (_Float16)ssp_f(fmaf(c0v, w0, c1v * w1v));
            }
            const _Float16* bhp = w2f + (size_t)(kt * 8) * 512 + (size_t)lane * 8;
            #pragma unroll
            for (int nt = 0; nt < 8; ++nt) {
                half8 bh = *reinterpret_cast<const half8*>(bhp + nt * 512);
                acc[nt] = __builtin_amdgcn_mfma_f32_16x16x32_f16(ah, bh, acc[nt], 0, 0, 0);
            }
        }

        // ---- epilogue: ssp + per-kt fp16 transpose, combine vs V frags ----
        f32x4 T0 = {0.f, 0.f, 0.f, 0.f};
        f32x4 T1 = {0.f, 0.f, 0.f, 0.f};
        #pragma unroll
        for (int kt = 0; kt < 4; ++kt) {
            #pragma unroll
            for (int ntl = 0; ntl < 2; ++ntl)
                #pragma unroll
                for (int reg = 0; reg < 4; ++reg)
                    sH2t[wv][quad * 4 + reg][ntl * 16 + m] =
                        (_Float16)ssp_f(acc[kt * 2 + ntl][reg] * INV_SQRT_H);
            half8 ah2 = *reinterpret_cast<const half8*>(&sH2t[wv][m][quad * 8]);
            half8 bv = *reinterpret_cast<const half8*>(sVf + (bl * 4 + kt) * 512 + lane * 8);
            if (kt & 1) T1 = __builtin_amdgcn_mfma_f32_16x16x32_f16(ah2, bv, T1, 0, 0, 0);
            else        T0 = __builtin_amdgcn_mfma_f32_16x16x32_f16(ah2, bv, T0, 0, 0, 0);
        }

        // G-weight (T C-layout: col=lane&15=cm, row=quad*4+reg=a-local)
        const int comp = (m >= 1 && m <= 8) ? (m - 1) : 0;
        float ps[4];
        #pragma unroll
        for (int reg = 0; reg < 4; ++reg) {
            const int row = quad * 4 + reg;
            const float Tv = T0[reg] + T1[reg];
            const float yv = sYw[wv][row][comp];
            const float g = (m == 0) ? 1.0f : ((m <= 8) ? yv : 0.0f);
            ps[reg] = Tv * g;
        }
        #pragma unroll
        for (int off = 1; off < 16; off <<= 1)
            #pragma unroll
            for (int reg = 0; reg < 4; ++reg)
                ps[reg] += __shfl_xor(ps[reg], off);
        #pragma unroll
        for (int reg = 0; reg < 4; ++reg) outAcc[reg] += ps[reg];
    }

    // ---- write partial[z][bg][a]: lanes m==0 hold a = wv*16 + quad*4 + reg ----
    if (m == 0) {
        float4 st;
        st.x = outAcc[0]; st.y = outAcc[1]; st.z = outAcc[2]; st.w = outAcc[3];
        *reinterpret_cast<float4*>(partial + ((size_t)(z * 16 + bg)) * 64 + wv * 16 + quad * 4) = st;
    }
}

// ---------------------------------------------------------------------------
// finalize: out[z,a] = sp( (sum_bg partial) / sqrt(n_atoms) ) * mask
// ---------------------------------------------------------------------------
__global__ __launch_bounds__(64, 8)
void finalize(const float* __restrict__ partial, const float* __restrict__ mask,
              float* __restrict__ out) {
    const int z = blockIdx.x, a = threadIdx.x;
    const float mk = mask[z * 64 + a];
    float s = mk;
    #pragma unroll
    for (int off = 32; off > 0; off >>= 1) s += __shfl_xor(s, off);
    const float inv = rsqrtf(s);
    float acc = 0.f;
    #pragma unroll
    for (int bg = 0; bg < 16; ++bg)
        acc += partial[((size_t)(z * 16 + bg)) * 64 + a];
    out[z * 64 + a] = sp_f(acc * inv) * mk;
}

extern "C" void kernel_launch(void* const* d_in, const int* in_sizes, int n_in,
                              void* d_out, int out_size, void* d_ws, size_t ws_size,
                              hipStream_t stream) {
    const float* rep  = (const float*)d_in[0];
    const float* geom = (const float*)d_in[1];
    const float* mask = (const float*)d_in[2];
    const float* W1   = (const float*)d_in[3];
    const float* W2   = (const float*)d_in[4];
    const float* W3   = (const float*)d_in[5];
    float* out = (float*)d_out;

    _Float16* w2f = (_Float16*)d_ws;                       // 32768 B
    float* partial = (float*)((char*)d_ws + 32768);        // 64*16*64*4 = 262144 B

    w2half<<<16, 256, 0, stream>>>(W2, w2f);
    pair4<<<dim3(16, 64), 256, 0, stream>>>(rep, geom, W1, W3, w2f, partial);
    finalize<<<64, 64, 0, stream>>>(partial, mask, out);
}